// Round 5
// baseline (67.829 us; speedup 1.0000x reference)
//
#include <hip/hip_runtime.h>
#include <hip/hip_bf16.h>

#define DIM 256
#define NAGENT 64
#define NBATCH 256

typedef __bf16 bf16_t;
typedef bf16_t bf16x4 __attribute__((ext_vector_type(4)));
typedef bf16_t bf16x8 __attribute__((ext_vector_type(8)));
typedef float f32x4 __attribute__((ext_vector_type(4)));

// Single kernel, 256 blocks x 512 threads (1 block/CU, all co-resident).
// Block b:
//   A) issue h[b] loads (8 x f32x4 per thread, held in regs)
//   B) prep: Wc[b] = bf16(Wh[b] @ Ws @ Wa), bc[b]; publish via fence+atomicAdd
//   C) column sums + g build (bf16, XOR-swizzled LDS)
//   D) spin until all 256 Wc rows published (expected ~0 wait), fence
//   E) MFMA GEMM out[b] = relu(g @ Wc^T + bc)
__global__ __launch_bounds__(512) void mac_one_kernel(
    const float* __restrict__ h,
    const float* __restrict__ Wh, const float* __restrict__ Ws,
    const float* __restrict__ Wa, const float* __restrict__ ba,
    const float* __restrict__ bs, const float* __restrict__ bh,
    bf16_t* __restrict__ Wc, float* __restrict__ bcw,
    unsigned int* ready, float* __restrict__ out) {
  const int b = blockIdx.x;
  const int t = threadIdx.x;
  const int cg = t & 63;   // column group: cols cg*4..+3 (also prep col group)
  const int rg = t >> 6;   // wave index 0..7 (rows rg*8..+7; prep k-chunk)

  __shared__ __align__(16) bf16_t g[NAGENT * DIM];  // 32 KB
  __shared__ f32x4 ps[8][64];                       // 8 KB  h col-sum partials
  __shared__ f32x4 part[8][64];                     // 8 KB  prep partials
  __shared__ float t1l[DIM];                        // 1 KB

  const float* hb = h + (size_t)b * NAGENT * DIM;

  // ---- A: issue h loads (kept in registers across prep) ----
  f32x4 v[8];
#pragma unroll
  for (int i = 0; i < 8; ++i)
    v[i] = *(const f32x4*)&hb[(rg * 8 + i) * DIM + cg * 4];

  // ---- B stage 1: t1 = Wh[b] @ Ws (k-chunk rg, cols cg*4..+3) ----
  {
    f32x4 a = {0.f, 0.f, 0.f, 0.f};
#pragma unroll
    for (int ki = 0; ki < 32; ++ki) {
      const int k = rg * 32 + ki;
      const float wv = Wh[b * DIM + k];  // wave-uniform -> scalar load
      a += wv * *(const f32x4*)&Ws[k * DIM + cg * 4];
    }
    part[rg][cg] = a;
  }
  __syncthreads();  // also drains h loads (vmcnt0)
  if (t < 64) {
    f32x4 s = part[0][t];
#pragma unroll
    for (int r = 1; r < 8; ++r) s += part[r][t];
    *(f32x4*)&t1l[t * 4] = s;
  }
  __syncthreads();

  // ---- B stage 2: Wc row = t1 @ Wa ; also h column-sum partials ----
  {
    f32x4 a = {0.f, 0.f, 0.f, 0.f};
#pragma unroll
    for (int ki = 0; ki < 32; ++ki) {
      const int k = rg * 32 + ki;
      a += t1l[k] * *(const f32x4*)&Wa[k * DIM + cg * 4];
    }
    f32x4 s4 = v[0];
#pragma unroll
    for (int i = 1; i < 8; ++i) s4 += v[i];
    ps[rg][cg] = s4;
    part[rg][cg] = a;
  }
  __syncthreads();

  // ---- B finalize (wave 0) + publish; C: hs + g build (all) ----
  if (t < 64) {
    f32x4 s = part[0][t];
#pragma unroll
    for (int r = 1; r < 8; ++r) s += part[r][t];
    bf16x4 wb;
    wb[0] = (bf16_t)s[0]; wb[1] = (bf16_t)s[1];
    wb[2] = (bf16_t)s[2]; wb[3] = (bf16_t)s[3];
    *(bf16x4*)&Wc[b * DIM + t * 4] = wb;
    // bc[b] = dot(t1,ba) + dot(Wh[b],bs) + bh[b]
    const f32x4 t14 = *(const f32x4*)&t1l[t * 4];
    const f32x4 ba4 = *(const f32x4*)&ba[t * 4];
    const f32x4 wh4 = *(const f32x4*)&Wh[b * DIM + t * 4];
    const f32x4 bs4 = *(const f32x4*)&bs[t * 4];
    const f32x4 pp = t14 * ba4 + wh4 * bs4;
    float p = pp[0] + pp[1] + pp[2] + pp[3];
#pragma unroll
    for (int s2 = 32; s2 > 0; s2 >>= 1) p += __shfl_down(p, s2, 64);
    if (t == 0) {
      bcw[b] = p + bh[b];
      __threadfence();          // release: Wc row + bcw visible device-wide
      atomicAdd(ready, 1u);     // device-scope
    }
  }

  f32x4 hs = ps[0][cg];
#pragma unroll
  for (int r = 1; r < 8; ++r) hs += ps[r][cg];
  const float inv = 1.0f / 63.0f;
#pragma unroll
  for (int i = 0; i < 8; ++i) {
    const int row = rg * 8 + i;
    const f32x4 gv = (hs - v[i]) * inv;
    bf16x4 gb;
    gb[0] = (bf16_t)gv[0]; gb[1] = (bf16_t)gv[1];
    gb[2] = (bf16_t)gv[2]; gb[3] = (bf16_t)gv[3];
    *(bf16x4*)&g[row * DIM + ((cg * 4) ^ ((row & 7) << 3))] = gb;
  }
  __syncthreads();

  // ---- D: wait for all 256 Wc rows ----
  if (t == 0) {
    while (__hip_atomic_load(ready, __ATOMIC_ACQUIRE,
                             __HIP_MEMORY_SCOPE_AGENT) < NBATCH)
      __builtin_amdgcn_s_sleep(4);
  }
  __syncthreads();
  __threadfence();  // acquire: invalidate stale cached Wc/bcw

  // ---- E: GEMM. wave w -> cols w*32..+31, rows 0..63 ----
  const int w = rg, lane = t & 63;
  const int lrow = lane & 15, lgrp = lane >> 4;

  f32x4 acc[4][2];
#pragma unroll
  for (int rt = 0; rt < 4; ++rt)
#pragma unroll
    for (int ct = 0; ct < 2; ++ct) acc[rt][ct] = (f32x4){0.f, 0.f, 0.f, 0.f};

#pragma unroll
  for (int kk = 0; kk < 8; ++kk) {
    const int k0 = kk * 32 + lgrp * 8;
    bf16x8 bfrag[2];
#pragma unroll
    for (int ct = 0; ct < 2; ++ct) {
      const int col = w * 32 + ct * 16 + lrow;
      bfrag[ct] = *(const bf16x8*)&Wc[col * DIM + k0];
    }
#pragma unroll
    for (int rt = 0; rt < 4; ++rt) {
      const int arow = rt * 16 + lrow;
      const bf16x8 afrag =
          *(const bf16x8*)&g[arow * DIM + (k0 ^ ((arow & 7) << 3))];
      acc[rt][0] = __builtin_amdgcn_mfma_f32_16x16x32_bf16(afrag, bfrag[0], acc[rt][0], 0, 0, 0);
      acc[rt][1] = __builtin_amdgcn_mfma_f32_16x16x32_bf16(afrag, bfrag[1], acc[rt][1], 0, 0, 0);
    }
  }

  // epilogue: C/D layout col=lane&15, row=(lane>>4)*4+reg
  float* ob = out + (size_t)b * NAGENT * DIM;
#pragma unroll
  for (int ct = 0; ct < 2; ++ct) {
    const int col = w * 32 + ct * 16 + lrow;
    const float bcv = bcw[col];
#pragma unroll
    for (int rt = 0; rt < 4; ++rt) {
#pragma unroll
      for (int r = 0; r < 4; ++r) {
        const int row = rt * 16 + lgrp * 4 + r;
        const float val = acc[rt][ct][r] + bcv;
        ob[row * DIM + col] = val > 0.f ? val : 0.f;
      }
    }
  }
}

extern "C" void kernel_launch(void* const* d_in, const int* in_sizes, int n_in,
                              void* d_out, int out_size, void* d_ws, size_t ws_size,
                              hipStream_t stream) {
  const float* h  = (const float*)d_in[0];  // hidden_state (16384,256)
  const float* Wa = (const float*)d_in[1];  // W_act (256,256)
  const float* ba = (const float*)d_in[2];  // b_act (256,)
  const float* Ws = (const float*)d_in[3];  // W_sum (256,256)
  const float* bs = (const float*)d_in[4];  // b_sum (256,)
  const float* Wh = (const float*)d_in[5];  // W_head (256,256)
  const float* bh = (const float*)d_in[6];  // b_head (256,)
  float* out = (float*)d_out;

  char* ws = (char*)d_ws;
  bf16_t* Wc  = (bf16_t*)ws;                        // 128 KB
  float*  bcw = (float*)(ws + 128 * 1024);          // 1 KB
  unsigned int* ready = (unsigned int*)(ws + 132 * 1024);

  // deterministic per-call reset of the publish counter (graph-capturable)
  hipMemsetAsync(ready, 0, sizeof(unsigned int), stream);

  mac_one_kernel<<<NBATCH, 512, 0, stream>>>(h, Wh, Ws, Wa, ba, bs, bh,
                                             Wc, bcw, ready, out);
}

// Round 6
// 65.613 us; speedup vs baseline: 1.0338x; 1.0338x over previous
//
#include <hip/hip_runtime.h>
#include <hip/hip_bf16.h>

#define DIM 256
#define NAGENT 64
#define NBATCH 256

typedef __bf16 bf16_t;
typedef bf16_t bf16x4 __attribute__((ext_vector_type(4)));
typedef bf16_t bf16x8 __attribute__((ext_vector_type(8)));
typedef float f32x4 __attribute__((ext_vector_type(4)));

// Single kernel, 256 blocks x 512 threads (1 block/CU, all co-resident).
// Block b:
//   A) issue h[b] loads (8 x f32x4 per thread, held in regs)
//   B) prep: Wc[b] = bf16(Wh[b] @ Ws @ Wa), bc[b]; publish: release fence + atomicAdd
//   C) column sums + g build (bf16, XOR-swizzled LDS)
//   D) spin with RELAXED polls (no L2-invalidate storm) until all 256 rows
//      published; then ONE acquire fence per block
//   E) MFMA GEMM out[b] = relu(g @ Wc^T + bc)
__global__ __launch_bounds__(512) void mac_one_kernel(
    const float* __restrict__ h,
    const float* __restrict__ Wh, const float* __restrict__ Ws,
    const float* __restrict__ Wa, const float* __restrict__ ba,
    const float* __restrict__ bs, const float* __restrict__ bh,
    bf16_t* __restrict__ Wc, float* __restrict__ bcw,
    unsigned int* ready, float* __restrict__ out) {
  const int b = blockIdx.x;
  const int t = threadIdx.x;
  const int cg = t & 63;   // column group: cols cg*4..+3 (also prep col group)
  const int rg = t >> 6;   // wave index 0..7 (rows rg*8..+7; prep k-chunk)

  __shared__ __align__(16) bf16_t g[NAGENT * DIM];  // 32 KB
  __shared__ f32x4 ps[8][64];                       // 8 KB  h col-sum partials
  __shared__ f32x4 part[8][64];                     // 8 KB  prep partials
  __shared__ float t1l[DIM];                        // 1 KB

  const float* hb = h + (size_t)b * NAGENT * DIM;

  // ---- A: issue h loads (kept in registers across prep) ----
  f32x4 v[8];
#pragma unroll
  for (int i = 0; i < 8; ++i)
    v[i] = *(const f32x4*)&hb[(rg * 8 + i) * DIM + cg * 4];

  // ---- B stage 1: t1 = Wh[b] @ Ws (k-chunk rg, cols cg*4..+3) ----
  {
    f32x4 a = {0.f, 0.f, 0.f, 0.f};
#pragma unroll
    for (int ki = 0; ki < 32; ++ki) {
      const int k = rg * 32 + ki;
      const float wv = Wh[b * DIM + k];  // wave-uniform -> scalar load
      a += wv * *(const f32x4*)&Ws[k * DIM + cg * 4];
    }
    part[rg][cg] = a;
  }
  __syncthreads();  // also drains h loads (vmcnt0)
  if (t < 64) {
    f32x4 s = part[0][t];
#pragma unroll
    for (int r = 1; r < 8; ++r) s += part[r][t];
    *(f32x4*)&t1l[t * 4] = s;
  }
  __syncthreads();

  // ---- B stage 2: Wc row = t1 @ Wa ; also h column-sum partials ----
  {
    f32x4 a = {0.f, 0.f, 0.f, 0.f};
#pragma unroll
    for (int ki = 0; ki < 32; ++ki) {
      const int k = rg * 32 + ki;
      a += t1l[k] * *(const f32x4*)&Wa[k * DIM + cg * 4];
    }
    f32x4 s4 = v[0];
#pragma unroll
    for (int i = 1; i < 8; ++i) s4 += v[i];
    ps[rg][cg] = s4;
    part[rg][cg] = a;
  }
  __syncthreads();

  // ---- B finalize (wave 0) + publish; C: hs + g build (all) ----
  if (t < 64) {
    f32x4 s = part[0][t];
#pragma unroll
    for (int r = 1; r < 8; ++r) s += part[r][t];
    bf16x4 wb;
    wb[0] = (bf16_t)s[0]; wb[1] = (bf16_t)s[1];
    wb[2] = (bf16_t)s[2]; wb[3] = (bf16_t)s[3];
    *(bf16x4*)&Wc[b * DIM + t * 4] = wb;
    // bc[b] = dot(t1,ba) + dot(Wh[b],bs) + bh[b]
    const f32x4 t14 = *(const f32x4*)&t1l[t * 4];
    const f32x4 ba4 = *(const f32x4*)&ba[t * 4];
    const f32x4 wh4 = *(const f32x4*)&Wh[b * DIM + t * 4];
    const f32x4 bs4 = *(const f32x4*)&bs[t * 4];
    const f32x4 pp = t14 * ba4 + wh4 * bs4;
    float p = pp[0] + pp[1] + pp[2] + pp[3];
#pragma unroll
    for (int s2 = 32; s2 > 0; s2 >>= 1) p += __shfl_down(p, s2, 64);
    if (t == 0) {
      bcw[b] = p + bh[b];
      __threadfence();          // release: Wc row + bcw visible device-wide
      atomicAdd(ready, 1u);     // device-scope
    }
  }

  f32x4 hs = ps[0][cg];
#pragma unroll
  for (int r = 1; r < 8; ++r) hs += ps[r][cg];
  const float inv = 1.0f / 63.0f;
#pragma unroll
  for (int i = 0; i < 8; ++i) {
    const int row = rg * 8 + i;
    const f32x4 gv = (hs - v[i]) * inv;
    bf16x4 gb;
    gb[0] = (bf16_t)gv[0]; gb[1] = (bf16_t)gv[1];
    gb[2] = (bf16_t)gv[2]; gb[3] = (bf16_t)gv[3];
    *(bf16x4*)&g[row * DIM + ((cg * 4) ^ ((row & 7) << 3))] = gb;
  }
  __syncthreads();

  // ---- D: wait for all 256 Wc rows. RELAXED poll (no invalidate storm);
  //      single acquire fence after exit. ----
  if (t == 0) {
    while (__hip_atomic_load(ready, __ATOMIC_RELAXED,
                             __HIP_MEMORY_SCOPE_AGENT) < NBATCH)
      __builtin_amdgcn_s_sleep(4);
  }
  __syncthreads();
  __threadfence();  // acquire: invalidate stale cached Wc/bcw (once per block)

  // ---- E: GEMM. wave w -> cols w*32..+31, rows 0..63 ----
  const int w = rg, lane = t & 63;
  const int lrow = lane & 15, lgrp = lane >> 4;

  f32x4 acc[4][2];
#pragma unroll
  for (int rt = 0; rt < 4; ++rt)
#pragma unroll
    for (int ct = 0; ct < 2; ++ct) acc[rt][ct] = (f32x4){0.f, 0.f, 0.f, 0.f};

#pragma unroll
  for (int kk = 0; kk < 8; ++kk) {
    const int k0 = kk * 32 + lgrp * 8;
    bf16x8 bfrag[2];
#pragma unroll
    for (int ct = 0; ct < 2; ++ct) {
      const int col = w * 32 + ct * 16 + lrow;
      bfrag[ct] = *(const bf16x8*)&Wc[col * DIM + k0];
    }
#pragma unroll
    for (int rt = 0; rt < 4; ++rt) {
      const int arow = rt * 16 + lrow;
      const bf16x8 afrag =
          *(const bf16x8*)&g[arow * DIM + (k0 ^ ((arow & 7) << 3))];
      acc[rt][0] = __builtin_amdgcn_mfma_f32_16x16x32_bf16(afrag, bfrag[0], acc[rt][0], 0, 0, 0);
      acc[rt][1] = __builtin_amdgcn_mfma_f32_16x16x32_bf16(afrag, bfrag[1], acc[rt][1], 0, 0, 0);
    }
  }

  // epilogue: C/D layout col=lane&15, row=(lane>>4)*4+reg
  float* ob = out + (size_t)b * NAGENT * DIM;
#pragma unroll
  for (int ct = 0; ct < 2; ++ct) {
    const int col = w * 32 + ct * 16 + lrow;
    const float bcv = bcw[col];
#pragma unroll
    for (int rt = 0; rt < 4; ++rt) {
#pragma unroll
      for (int r = 0; r < 4; ++r) {
        const int row = rt * 16 + lgrp * 4 + r;
        const float val = acc[rt][ct][r] + bcv;
        ob[row * DIM + col] = val > 0.f ? val : 0.f;
      }
    }
  }
}

extern "C" void kernel_launch(void* const* d_in, const int* in_sizes, int n_in,
                              void* d_out, int out_size, void* d_ws, size_t ws_size,
                              hipStream_t stream) {
  const float* h  = (const float*)d_in[0];  // hidden_state (16384,256)
  const float* Wa = (const float*)d_in[1];  // W_act (256,256)
  const float* ba = (const float*)d_in[2];  // b_act (256,)
  const float* Ws = (const float*)d_in[3];  // W_sum (256,256)
  const float* bs = (const float*)d_in[4];  // b_sum (256,)
  const float* Wh = (const float*)d_in[5];  // W_head (256,256)
  const float* bh = (const float*)d_in[6];  // b_head (256,)
  float* out = (float*)d_out;

  char* ws = (char*)d_ws;
  bf16_t* Wc  = (bf16_t*)ws;                        // 128 KB
  float*  bcw = (float*)(ws + 128 * 1024);          // 1 KB
  unsigned int* ready = (unsigned int*)(ws + 132 * 1024);

  // deterministic per-call reset of the publish counter (graph-capturable)
  hipMemsetAsync(ready, 0, sizeof(unsigned int), stream);

  mac_one_kernel<<<NBATCH, 512, 0, stream>>>(h, Wh, Ws, Wa, ba, bs, bh,
                                             Wc, bcw, ready, out);
}

// Round 7
// 23.519 us; speedup vs baseline: 2.8840x; 2.7898x over previous
//
#include <hip/hip_runtime.h>
#include <hip/hip_bf16.h>

#define DIM 256
#define NAGENT 64
#define NBATCH 256

typedef __bf16 bf16_t;
typedef bf16_t bf16x4 __attribute__((ext_vector_type(4)));
typedef bf16_t bf16x8 __attribute__((ext_vector_type(8)));
typedef float f32x4 __attribute__((ext_vector_type(4)));

// Prep: block b computes row b of Wc = bf16(Wh @ Ws @ Wa) and bc[b].
// (verbatim from R4 — verified good)
__global__ __launch_bounds__(1024) void prep_kernel(
    const float* __restrict__ Wh, const float* __restrict__ Ws,
    const float* __restrict__ Wa, const float* __restrict__ ba,
    const float* __restrict__ bs, const float* __restrict__ bh,
    bf16_t* __restrict__ Wc, float* __restrict__ bcw) {
  const int b = blockIdx.x;
  const int t = threadIdx.x;
  const int jg = t & 63;
  const int kc = t >> 6;

  __shared__ float whl[DIM];
  __shared__ float t1l[DIM];
  __shared__ f32x4 part[16][64];
  __shared__ float red[256];

  if (t < DIM) whl[t] = Wh[b * DIM + t];
  __syncthreads();

  // stage 1: t1 = whl @ Ws
  {
    f32x4 a = {0.f, 0.f, 0.f, 0.f};
#pragma unroll
    for (int ki = 0; ki < 16; ++ki) {
      const int k = kc * 16 + ki;
      const f32x4 w4 = *(const f32x4*)&Ws[k * DIM + jg * 4];
      a += whl[k] * w4;
    }
    part[kc][jg] = a;
  }
  __syncthreads();
  if (t < 64) {
    f32x4 s = part[0][t];
#pragma unroll
    for (int kc2 = 1; kc2 < 16; ++kc2) s += part[kc2][t];
    *(f32x4*)&t1l[t * 4] = s;
  }
  __syncthreads();

  // stage 2: Wc row = t1 @ Wa ; bias partials
  {
    f32x4 a = {0.f, 0.f, 0.f, 0.f};
#pragma unroll
    for (int ki = 0; ki < 16; ++ki) {
      const int k = kc * 16 + ki;
      const f32x4 w4 = *(const f32x4*)&Wa[k * DIM + jg * 4];
      a += t1l[k] * w4;
    }
    if (t < 256) red[t] = t1l[t] * ba[t] + whl[t] * bs[t];
    part[kc][jg] = a;
  }
  __syncthreads();
  if (t < 64) {
    f32x4 s = part[0][t];
#pragma unroll
    for (int kc2 = 1; kc2 < 16; ++kc2) s += part[kc2][t];
    bf16x4 wb;
    wb[0] = (bf16_t)s[0]; wb[1] = (bf16_t)s[1];
    wb[2] = (bf16_t)s[2]; wb[3] = (bf16_t)s[3];
    *(bf16x4*)&Wc[b * DIM + t * 4] = wb;
    float p = red[t] + red[t + 64] + red[t + 128] + red[t + 192];
#pragma unroll
    for (int s2 = 32; s2 > 0; s2 >>= 1) p += __shfl_down(p, s2, 64);
    if (t == 0) bcw[b] = p + bh[b];
  }
}

// Fused main, split-column for 2 blocks/CU phase overlap.
// Block (b, half): builds full g for batch b (64x256 bf16, swizzled LDS),
// computes output cols half*128 .. half*128+127.
// 256 threads = 4 waves; wave w -> cols half*128 + w*32 .. +31, rows 0..63.
__global__ __launch_bounds__(256) void fused_kernel(
    const float* __restrict__ h, const bf16_t* __restrict__ Wc,
    const float* __restrict__ bcw, float* __restrict__ out) {
  const int b = blockIdx.x;
  const int half = blockIdx.y;
  const int t = threadIdx.x;

  __shared__ __align__(16) bf16_t g[NAGENT * DIM];  // 32 KB, XOR-swizzled
  __shared__ f32x4 ps[4][64];                       // 4 KB

  const float* hb = h + (size_t)b * NAGENT * DIM;
  const int cg = t & 63;   // cols cg*4 .. +3
  const int rg = t >> 6;   // row quartet: rows rg*16 .. +15

  // single pass over h: 16 rows x 4 cols per thread
  f32x4 v[16];
  f32x4 s4 = {0.f, 0.f, 0.f, 0.f};
#pragma unroll
  for (int i = 0; i < 16; ++i) {
    v[i] = *(const f32x4*)&hb[(rg * 16 + i) * DIM + cg * 4];
    s4 += v[i];
  }
  ps[rg][cg] = s4;
  __syncthreads();
  f32x4 hs = ps[0][cg];
#pragma unroll
  for (int r = 1; r < 4; ++r) hs += ps[r][cg];

  const float inv = 1.0f / 63.0f;
#pragma unroll
  for (int i = 0; i < 16; ++i) {
    const int row = rg * 16 + i;
    const f32x4 gv = (hs - v[i]) * inv;
    bf16x4 gb;
    gb[0] = (bf16_t)gv[0]; gb[1] = (bf16_t)gv[1];
    gb[2] = (bf16_t)gv[2]; gb[3] = (bf16_t)gv[3];
    *(bf16x4*)&g[row * DIM + ((cg * 4) ^ ((row & 7) << 3))] = gb;
  }
  __syncthreads();

  // GEMM: wave w -> cols half*128 + w*32 .. +31, rows 0..63
  const int w = rg, lane = t & 63;
  const int lrow = lane & 15, lgrp = lane >> 4;
  const int colbase = half * 128 + w * 32;

  f32x4 acc[4][2];
#pragma unroll
  for (int rt = 0; rt < 4; ++rt)
#pragma unroll
    for (int ct = 0; ct < 2; ++ct) acc[rt][ct] = (f32x4){0.f, 0.f, 0.f, 0.f};

#pragma unroll
  for (int kk = 0; kk < 8; ++kk) {
    const int k0 = kk * 32 + lgrp * 8;
    bf16x8 bfrag[2];
#pragma unroll
    for (int ct = 0; ct < 2; ++ct) {
      const int col = colbase + ct * 16 + lrow;
      bfrag[ct] = *(const bf16x8*)&Wc[col * DIM + k0];
    }
#pragma unroll
    for (int rt = 0; rt < 4; ++rt) {
      const int arow = rt * 16 + lrow;
      const bf16x8 afrag =
          *(const bf16x8*)&g[arow * DIM + (k0 ^ ((arow & 7) << 3))];
      acc[rt][0] = __builtin_amdgcn_mfma_f32_16x16x32_bf16(afrag, bfrag[0], acc[rt][0], 0, 0, 0);
      acc[rt][1] = __builtin_amdgcn_mfma_f32_16x16x32_bf16(afrag, bfrag[1], acc[rt][1], 0, 0, 0);
    }
  }

  // epilogue: C/D layout col=lane&15, row=(lane>>4)*4+reg
  float* ob = out + (size_t)b * NAGENT * DIM;
#pragma unroll
  for (int ct = 0; ct < 2; ++ct) {
    const int col = colbase + ct * 16 + lrow;
    const float bcv = bcw[col];
#pragma unroll
    for (int rt = 0; rt < 4; ++rt) {
#pragma unroll
      for (int r = 0; r < 4; ++r) {
        const int row = rt * 16 + lgrp * 4 + r;
        const float val = acc[rt][ct][r] + bcv;
        ob[row * DIM + col] = val > 0.f ? val : 0.f;
      }
    }
  }
}

extern "C" void kernel_launch(void* const* d_in, const int* in_sizes, int n_in,
                              void* d_out, int out_size, void* d_ws, size_t ws_size,
                              hipStream_t stream) {
  const float* h  = (const float*)d_in[0];  // hidden_state (16384,256)
  const float* Wa = (const float*)d_in[1];  // W_act (256,256)
  const float* ba = (const float*)d_in[2];  // b_act (256,)
  const float* Ws = (const float*)d_in[3];  // W_sum (256,256)
  const float* bs = (const float*)d_in[4];  // b_sum (256,)
  const float* Wh = (const float*)d_in[5];  // W_head (256,256)
  const float* bh = (const float*)d_in[6];  // b_head (256,)
  float* out = (float*)d_out;

  char* ws = (char*)d_ws;
  bf16_t* Wc  = (bf16_t*)ws;                 // 128 KB
  float*  bcw = (float*)(ws + 128 * 1024);   // 1 KB

  prep_kernel<<<NBATCH, 1024, 0, stream>>>(Wh, Ws, Wa, ba, bs, bh, Wc, bcw);
  fused_kernel<<<dim3(NBATCH, 2), 256, 0, stream>>>(h, Wc, bcw, out);
}